// Round 1
// baseline (4800.958 us; speedup 1.0000x reference)
//
#include <hip/hip_runtime.h>

// DependencyParser: 2× two-layer BiLSTM (word E=512, pos P=128), T=1024, B=1,
// then rank-1 edge scores S[i][j] = H[i]@w1 + H[j]@w2 + b, diag=0.
//
// Pipeline (all on `stream`):
//  1. poison h buffers to 0xFFFFFFFF (data-as-flag for the recurrence spin sync)
//  2. GEMM xg = x @ wih^T + bih + bhh   (layer 0, word + pos, both dirs)
//  3. rec_kernel: persistent-register LSTM recurrence (word f/b: 32 WGs each,
//     pos f/b: 4 WGs each; h published via agent-scope atomic stores)
//  4. concat layer-0 outputs
//  5. GEMM xg layer 1
//  6. rec_kernel layer 1
//  7. edge s1/s2 dots + S fill
//
// WS layout (floats): xg_w[2][1024][2048] | xg_p[2][1024][512] |
//   hw0_f,hw0_b,hw1_f,hw1_b (4x 1024*512) | hp0_f,hp0_b,hp1_f,hp1_b (4x 1024*128)
//   | wcat[1024][1024] | pcat[1024][256] | s1[1024] | s2[1024]  => ~36.7 MB

#define T_LEN 1024

// ---------------------------------------------------------------- poison ----
__global__ void poison_kernel(unsigned* p, int n) {
  int i = blockIdx.x * blockDim.x + threadIdx.x;
  int stride = gridDim.x * blockDim.x;
  for (; i < n; i += stride) p[i] = 0xFFFFFFFFu;
}

// ------------------------------------------------ GEMM C = A@W^T + b0 + b1 ----
// A: [M][K], W: [2][N][K] (z = direction), C: [2][M][N]. 64x64 tile, 256 thr.
__global__ __launch_bounds__(256) void gemm_bt(
    const float* __restrict__ A,
    const float* __restrict__ Wt,
    const float* __restrict__ B0,
    const float* __restrict__ B1,
    float* __restrict__ C,
    int M, int N, int K)
{
  const int z = blockIdx.z;
  const float* W  = Wt + (size_t)z * N * K;
  const float* b0 = B0 + (size_t)z * N;
  const float* b1 = B1 + (size_t)z * N;
  float* Cz = C + (size_t)z * M * N;

  __shared__ __align__(16) float As[16][64];
  __shared__ __align__(16) float Ws[16][64];

  const int tid = threadIdx.x;
  const int tx = tid & 15, ty = tid >> 4;
  const int brow = blockIdx.y * 64, bcol = blockIdx.x * 64;
  const int lr = tid >> 2;          // 0..63
  const int lk = (tid & 3) << 2;    // 0,4,8,12

  float acc[4][4] = {};

  for (int k0 = 0; k0 < K; k0 += 16) {
    float4 av = *(const float4*)(A + (size_t)(brow + lr) * K + k0 + lk);
    float4 wv = *(const float4*)(W + (size_t)(bcol + lr) * K + k0 + lk);
    __syncthreads();
    As[lk + 0][lr] = av.x; As[lk + 1][lr] = av.y;
    As[lk + 2][lr] = av.z; As[lk + 3][lr] = av.w;
    Ws[lk + 0][lr] = wv.x; Ws[lk + 1][lr] = wv.y;
    Ws[lk + 2][lr] = wv.z; Ws[lk + 3][lr] = wv.w;
    __syncthreads();
    #pragma unroll
    for (int kk = 0; kk < 16; ++kk) {
      float4 a = *(const float4*)&As[kk][ty << 2];
      float4 w = *(const float4*)&Ws[kk][tx << 2];
      float a4[4] = {a.x, a.y, a.z, a.w};
      float w4[4] = {w.x, w.y, w.z, w.w};
      #pragma unroll
      for (int i = 0; i < 4; ++i)
        #pragma unroll
        for (int j = 0; j < 4; ++j)
          acc[i][j] = fmaf(a4[i], w4[j], acc[i][j]);
    }
  }

  const int nb = bcol + (tx << 2);
  float bias[4];
  #pragma unroll
  for (int j = 0; j < 4; ++j) bias[j] = b0[nb + j] + b1[nb + j];
  #pragma unroll
  for (int i = 0; i < 4; ++i) {
    int m = brow + (ty << 2) + i;
    float4 out;
    out.x = acc[i][0] + bias[0];
    out.y = acc[i][1] + bias[1];
    out.z = acc[i][2] + bias[2];
    out.w = acc[i][3] + bias[3];
    *(float4*)(Cz + (size_t)m * N + nb) = out;
  }
}

// ---------------------------------------------------------- LSTM recurrence ----
// Persistent-register recurrence. Each WG owns NH = RPW/4 h-elements and the
// RPW = 4*NH corresponding gate rows of whh (kept in VGPRs). h is published
// through agent-scope atomic stores into a 0xFFFFFFFF-poisoned buffer;
// consumers spin on the data itself (h = sigmoid*tanh can never be NaN).
template<int H, int RPW, int PARTS>
__device__ __forceinline__ void lstm_body(
    int wg, const float* __restrict__ xg, const float* __restrict__ whh,
    float* hbuf, int rev)
{
  constexpr int NTH = RPW * PARTS;   // 256
  constexpr int NH  = RPW / 4;
  constexpr int CPP = H / PARTS;
  static_assert(NTH == 256, "block must be 256 threads");

  const int tid  = threadIdx.x;
  const int r    = tid / PARTS;      // local gate row
  const int p    = tid % PARTS;      // column part
  const int gate = r / NH;           // 0:i 1:f 2:g 3:o
  const int elem = r % NH;
  const int hbase = wg * NH;
  const int grow  = gate * H + hbase + elem;  // global gate row

  __shared__ __align__(16) float h_lds[PARTS][CPP + 4];  // +4 pad: bank spread
  __shared__ float gates[RPW];

  float w[CPP];
  #pragma unroll
  for (int c = 0; c < CPP; ++c)
    w[c] = whh[(size_t)grow * H + p * CPP + c];

  float cstate = 0.f;                 // valid for tid < NH
  unsigned* hb = (unsigned*)hbuf;

  for (int s = 0; s < T_LEN; ++s) {
    const int t = rev ? (T_LEN - 1 - s) : s;
    const float xgv = xg[(size_t)t * (4 * H) + grow];  // prefetch early

    if (s == 0) {
      for (int i = tid; i < H; i += NTH) h_lds[i / CPP][i % CPP] = 0.f;
    } else {
      const int tp = rev ? (t + 1) : (t - 1);
      unsigned* src = hb + (size_t)tp * H;
      for (int i = tid; i < H; i += NTH) {
        if (i < hbase || i >= hbase + NH) {   // own slice already in LDS
          unsigned u = __hip_atomic_load(src + i, __ATOMIC_RELAXED,
                                         __HIP_MEMORY_SCOPE_AGENT);
          while (u == 0xFFFFFFFFu) {
            __builtin_amdgcn_s_sleep(1);
            u = __hip_atomic_load(src + i, __ATOMIC_RELAXED,
                                  __HIP_MEMORY_SCOPE_AGENT);
          }
          h_lds[i / CPP][i % CPP] = __uint_as_float(u);
        }
      }
    }
    __syncthreads();

    const float4* h4 = (const float4*)&h_lds[p][0];
    float a0 = 0.f, a1 = 0.f, a2 = 0.f, a3 = 0.f;
    #pragma unroll
    for (int c4 = 0; c4 < CPP / 4; ++c4) {
      float4 hv = h4[c4];
      a0 = fmaf(w[4 * c4 + 0], hv.x, a0);
      a1 = fmaf(w[4 * c4 + 1], hv.y, a1);
      a2 = fmaf(w[4 * c4 + 2], hv.z, a2);
      a3 = fmaf(w[4 * c4 + 3], hv.w, a3);
    }
    float acc = (a0 + a1) + (a2 + a3);
    #pragma unroll
    for (int off = 1; off < PARTS; off <<= 1)
      acc += __shfl_xor(acc, off, 64);
    if (p == 0) gates[r] = acc + xgv;
    __syncthreads();

    if (tid < NH) {
      float gi = gates[0 * NH + tid];
      float gf = gates[1 * NH + tid];
      float gg = gates[2 * NH + tid];
      float go = gates[3 * NH + tid];
      float si = 1.f / (1.f + expf(-gi));
      float sf = 1.f / (1.f + expf(-gf));
      float so = 1.f / (1.f + expf(-go));
      float tg = tanhf(gg);
      cstate = fmaf(sf, cstate, si * tg);
      float h = so * tanhf(cstate);
      const int gidx = hbase + tid;
      h_lds[gidx / CPP][gidx % CPP] = h;   // own slice for next step
      __hip_atomic_store(hb + (size_t)t * H + gidx, __float_as_uint(h),
                         __ATOMIC_RELAXED, __HIP_MEMORY_SCOPE_AGENT);
    }
    // no trailing barrier needed: next-iter staging only writes non-own LDS
    // ranges and everyone re-syncs before the FMA reads.
  }
}

__global__ __launch_bounds__(256, 1) void rec_kernel(
    const float* xg_wf, const float* xg_wb, const float* whh_w,
    float* h_wf, float* h_wb,
    const float* xg_pf, const float* xg_pb, const float* whh_p,
    float* h_pf, float* h_pb)
{
  int b = blockIdx.x;
  if (b < 32)        lstm_body<512, 64, 4>(b,      xg_wf, whh_w,             h_wf, 0);
  else if (b < 64)   lstm_body<512, 64, 4>(b - 32, xg_wb, whh_w + 2048 * 512, h_wb, 1);
  else if (b < 68)   lstm_body<128, 128, 2>(b - 64, xg_pf, whh_p,             h_pf, 0);
  else               lstm_body<128, 128, 2>(b - 68, xg_pb, whh_p + 512 * 128, h_pb, 1);
}

// ------------------------------------------------------------------ concat ----
__global__ void concat_k(const float* __restrict__ wf, const float* __restrict__ wb,
                         const float* __restrict__ pf, const float* __restrict__ pb,
                         float* __restrict__ wcat, float* __restrict__ pcat)
{
  const int totw = T_LEN * 1024;
  const int totp = T_LEN * 256;
  int idx = blockIdx.x * blockDim.x + threadIdx.x;
  int stride = gridDim.x * blockDim.x;
  for (int e = idx; e < totw + totp; e += stride) {
    if (e < totw) {
      int t = e >> 10, d = e & 1023;
      wcat[e] = d < 512 ? wf[t * 512 + d] : wb[t * 512 + (d - 512)];
    } else {
      int e2 = e - totw;
      int t = e2 >> 8, d = e2 & 255;
      pcat[e2] = d < 128 ? pf[t * 128 + d] : pb[t * 128 + (d - 128)];
    }
  }
}

// ------------------------------------------------------------- edge scores ----
__global__ __launch_bounds__(256) void edge_s(
    const float* __restrict__ hwf, const float* __restrict__ hwb,
    const float* __restrict__ hpf, const float* __restrict__ hpb,
    const float* __restrict__ ew, float* s1, float* s2)
{
  const int i = blockIdx.x;
  const int tid = threadIdx.x;
  float a1 = 0.f, a2 = 0.f;
  for (int d = tid; d < 1280; d += 256) {
    float hv;
    if (d < 512)       hv = hwf[i * 512 + d];
    else if (d < 1024) hv = hwb[i * 512 + d - 512];
    else if (d < 1152) hv = hpf[i * 128 + d - 1024];
    else               hv = hpb[i * 128 + d - 1152];
    a1 = fmaf(hv, ew[d], a1);
    a2 = fmaf(hv, ew[1280 + d], a2);
  }
  #pragma unroll
  for (int off = 32; off > 0; off >>= 1) {
    a1 += __shfl_xor(a1, off, 64);
    a2 += __shfl_xor(a2, off, 64);
  }
  __shared__ float r1[4], r2[4];
  const int wid = tid >> 6;
  if ((tid & 63) == 0) { r1[wid] = a1; r2[wid] = a2; }
  __syncthreads();
  if (tid == 0) {
    s1[i] = (r1[0] + r1[1]) + (r1[2] + r1[3]);
    s2[i] = (r2[0] + r2[1]) + (r2[2] + r2[3]);
  }
}

__global__ __launch_bounds__(256) void sfill(
    const float* __restrict__ s1, const float* __restrict__ s2,
    const float* __restrict__ eb, float* __restrict__ out)
{
  int e = blockIdx.x * 256 + threadIdx.x;  // 0 .. 1024*1024-1
  int i = e >> 10, j = e & 1023;
  out[e] = (i == j) ? 0.f : s1[i] + s2[j] + eb[0];
}

// ------------------------------------------------------------------ launch ----
extern "C" void kernel_launch(void* const* d_in, const int* in_sizes, int n_in,
                              void* d_out, int out_size, void* d_ws, size_t ws_size,
                              hipStream_t stream)
{
  const float* words   = (const float*)d_in[0];
  const float* pos     = (const float*)d_in[1];
  const float* w_w0_ih = (const float*)d_in[2];
  const float* w_w0_hh = (const float*)d_in[3];
  const float* w_b0_ih = (const float*)d_in[4];
  const float* w_b0_hh = (const float*)d_in[5];
  const float* w_w1_ih = (const float*)d_in[6];
  const float* w_w1_hh = (const float*)d_in[7];
  const float* w_b1_ih = (const float*)d_in[8];
  const float* w_b1_hh = (const float*)d_in[9];
  const float* p_w0_ih = (const float*)d_in[10];
  const float* p_w0_hh = (const float*)d_in[11];
  const float* p_b0_ih = (const float*)d_in[12];
  const float* p_b0_hh = (const float*)d_in[13];
  const float* p_w1_ih = (const float*)d_in[14];
  const float* p_w1_hh = (const float*)d_in[15];
  const float* p_b1_ih = (const float*)d_in[16];
  const float* p_b1_hh = (const float*)d_in[17];
  const float* edge_w  = (const float*)d_in[18];
  const float* edge_b  = (const float*)d_in[19];

  float* ws = (float*)d_ws;
  float* xg_w  = ws;                       // [2][1024][2048] = 4,194,304
  float* xg_p  = ws + 4194304;             // [2][1024][512]  = 1,048,576
  float* hw0_f = ws + 5242880;             // [1024][512] each
  float* hw0_b = hw0_f + 524288;
  float* hw1_f = hw0_b + 524288;
  float* hw1_b = hw1_f + 524288;
  float* hp0_f = hw1_b + 524288;           // [1024][128] each
  float* hp0_b = hp0_f + 131072;
  float* hp1_f = hp0_b + 131072;
  float* hp1_b = hp1_f + 131072;
  float* wcat  = hp1_b + 131072;           // [1024][1024]
  float* pcat  = wcat + 1048576;           // [1024][256]
  float* s1    = pcat + 262144;
  float* s2    = s1 + 1024;
  // total = 9,177,088 floats = 36.7 MB of d_ws

  // 1. poison all h buffers (data-as-flag sync) — every call, since the
  //    harness does not re-poison between graph replays.
  poison_kernel<<<2048, 256, 0, stream>>>((unsigned*)hw0_f, 2621440);

  // 2. layer-0 input projections
  gemm_bt<<<dim3(32, 16, 2), 256, 0, stream>>>(words, w_w0_ih, w_b0_ih, w_b0_hh,
                                               xg_w, 1024, 2048, 512);
  gemm_bt<<<dim3(8, 16, 2), 256, 0, stream>>>(pos, p_w0_ih, p_b0_ih, p_b0_hh,
                                              xg_p, 1024, 512, 128);

  // 3. layer-0 recurrence (word f/b + pos f/b in one launch, 72 WGs)
  rec_kernel<<<72, 256, 0, stream>>>(xg_w, xg_w + 2097152, w_w0_hh, hw0_f, hw0_b,
                                     xg_p, xg_p + 524288, p_w0_hh, hp0_f, hp0_b);

  // 4. concat layer-0 outputs
  concat_k<<<2048, 256, 0, stream>>>(hw0_f, hw0_b, hp0_f, hp0_b, wcat, pcat);

  // 5. layer-1 input projections (xg buffers reused)
  gemm_bt<<<dim3(32, 16, 2), 256, 0, stream>>>(wcat, w_w1_ih, w_b1_ih, w_b1_hh,
                                               xg_w, 1024, 2048, 1024);
  gemm_bt<<<dim3(8, 16, 2), 256, 0, stream>>>(pcat, p_w1_ih, p_b1_ih, p_b1_hh,
                                              xg_p, 1024, 512, 256);

  // 6. layer-1 recurrence
  rec_kernel<<<72, 256, 0, stream>>>(xg_w, xg_w + 2097152, w_w1_hh, hw1_f, hw1_b,
                                     xg_p, xg_p + 524288, p_w1_hh, hp1_f, hp1_b);

  // 7. edge scores
  edge_s<<<1024, 256, 0, stream>>>(hw1_f, hw1_b, hp1_f, hp1_b, edge_w, s1, s2);
  sfill<<<4096, 256, 0, stream>>>(s1, s2, edge_b, (float*)d_out);
}

// Round 2
// 3453.461 us; speedup vs baseline: 1.3902x; 1.3902x over previous
//
#include <hip/hip_runtime.h>

// DependencyParser: 2× two-layer BiLSTM (word E=512, pos P=128), T=1024, B=1,
// then rank-1 edge scores S[i][j] = H[i]@w1 + H[j]@w2 + b, diag=0.
//
// R2 changes vs R1 (R1: 4801 us, rec_kernel 2x2300 us, latency-bound):
//  - word recurrence: 512-thr WGs, PARTS=8, single 8B atomic poll per thread
//    (was 2 serialized 4B spins + s_sleep) -> 1 MALL round trip per step.
//  - pos recurrence: single WG per direction, all-LDS, no global sync at all.
//  - fast sigmoid/tanh via __expf.
//  - poison only the 4 word h buffers.

#define T_LEN 1024

// ---------------------------------------------------------------- poison ----
__global__ void poison_kernel(unsigned* p, int n) {
  int i = blockIdx.x * blockDim.x + threadIdx.x;
  int stride = gridDim.x * blockDim.x;
  for (; i < n; i += stride) p[i] = 0xFFFFFFFFu;
}

// ------------------------------------------------ GEMM C = A@W^T + b0 + b1 ----
// A: [M][K], W: [2][N][K] (z = direction), C: [2][M][N]. 64x64 tile, 256 thr.
__global__ __launch_bounds__(256) void gemm_bt(
    const float* __restrict__ A,
    const float* __restrict__ Wt,
    const float* __restrict__ B0,
    const float* __restrict__ B1,
    float* __restrict__ C,
    int M, int N, int K)
{
  const int z = blockIdx.z;
  const float* W  = Wt + (size_t)z * N * K;
  const float* b0 = B0 + (size_t)z * N;
  const float* b1 = B1 + (size_t)z * N;
  float* Cz = C + (size_t)z * M * N;

  __shared__ __align__(16) float As[16][64];
  __shared__ __align__(16) float Ws[16][64];

  const int tid = threadIdx.x;
  const int tx = tid & 15, ty = tid >> 4;
  const int brow = blockIdx.y * 64, bcol = blockIdx.x * 64;
  const int lr = tid >> 2;          // 0..63
  const int lk = (tid & 3) << 2;    // 0,4,8,12

  float acc[4][4] = {};

  for (int k0 = 0; k0 < K; k0 += 16) {
    float4 av = *(const float4*)(A + (size_t)(brow + lr) * K + k0 + lk);
    float4 wv = *(const float4*)(W + (size_t)(bcol + lr) * K + k0 + lk);
    __syncthreads();
    As[lk + 0][lr] = av.x; As[lk + 1][lr] = av.y;
    As[lk + 2][lr] = av.z; As[lk + 3][lr] = av.w;
    Ws[lk + 0][lr] = wv.x; Ws[lk + 1][lr] = wv.y;
    Ws[lk + 2][lr] = wv.z; Ws[lk + 3][lr] = wv.w;
    __syncthreads();
    #pragma unroll
    for (int kk = 0; kk < 16; ++kk) {
      float4 a = *(const float4*)&As[kk][ty << 2];
      float4 w = *(const float4*)&Ws[kk][tx << 2];
      float a4[4] = {a.x, a.y, a.z, a.w};
      float w4[4] = {w.x, w.y, w.z, w.w};
      #pragma unroll
      for (int i = 0; i < 4; ++i)
        #pragma unroll
        for (int j = 0; j < 4; ++j)
          acc[i][j] = fmaf(a4[i], w4[j], acc[i][j]);
    }
  }

  const int nb = bcol + (tx << 2);
  float bias[4];
  #pragma unroll
  for (int j = 0; j < 4; ++j) bias[j] = b0[nb + j] + b1[nb + j];
  #pragma unroll
  for (int i = 0; i < 4; ++i) {
    int m = brow + (ty << 2) + i;
    float4 out;
    out.x = acc[i][0] + bias[0];
    out.y = acc[i][1] + bias[1];
    out.z = acc[i][2] + bias[2];
    out.w = acc[i][3] + bias[3];
    *(float4*)(Cz + (size_t)m * N + nb) = out;
  }
}

// --------------------------------------------------------- fast activations ----
__device__ __forceinline__ float fsigmoid(float x) {
  return 1.f / (1.f + __expf(-x));
}
__device__ __forceinline__ float ftanh(float x) {
  return 2.f / (1.f + __expf(-2.f * x)) - 1.f;
}

// --------------------------------------------------- word LSTM (cross-WG) ----
// 32 WGs x 512 thr per direction. WG owns NH=16 h-elems (64 gate rows).
// PARTS=8 column split -> w[64] per thread. h published as fp32 through
// agent-scope stores into a 0xFFFFFFFF-poisoned buffer; consumers poll one
// 8B granule per thread (data-as-flag: h=sigmoid*tanh is never NaN).
__device__ __forceinline__ void word_body(
    int wg, const float* __restrict__ xg, const float* __restrict__ whh,
    float* hbuf, int rev)
{
  const int tid  = threadIdx.x;
  const int r    = tid >> 3;         // 0..63  gate row within WG
  const int p    = tid & 7;          // column part
  const int gate = r >> 4;
  const int elem = r & 15;
  const int grow = gate * 512 + wg * 16 + elem;

  __shared__ __align__(16) float h_lds[8][68];   // part-major, 68 = stagger pad
  __shared__ float gates[64];

  float w[64];
  #pragma unroll
  for (int c = 0; c < 64; ++c)
    w[c] = whh[(size_t)grow * 512 + p * 64 + c];

  float cstate = 0.f;                 // valid for tid < 16
  unsigned long long* hb64 = (unsigned long long*)hbuf;
  unsigned* hb32 = (unsigned*)hbuf;

  for (int s = 0; s < T_LEN; ++s) {
    const int t = rev ? (T_LEN - 1 - s) : s;
    const float xgv = xg[(size_t)t * 2048 + grow];

    if (tid < 256) {
      const int f0 = tid << 1;
      float v0, v1;
      if (s == 0) {
        v0 = 0.f; v1 = 0.f;
      } else {
        const int tp = rev ? (t + 1) : (t - 1);
        unsigned long long u = __hip_atomic_load(hb64 + (size_t)tp * 256 + tid,
                                                 __ATOMIC_RELAXED,
                                                 __HIP_MEMORY_SCOPE_AGENT);
        while ((unsigned)u == 0xFFFFFFFFu || (unsigned)(u >> 32) == 0xFFFFFFFFu) {
          u = __hip_atomic_load(hb64 + (size_t)tp * 256 + tid,
                                __ATOMIC_RELAXED, __HIP_MEMORY_SCOPE_AGENT);
        }
        v0 = __uint_as_float((unsigned)u);
        v1 = __uint_as_float((unsigned)(u >> 32));
      }
      h_lds[f0 >> 6][f0 & 63] = v0;
      h_lds[(f0 + 1) >> 6][(f0 + 1) & 63] = v1;
    }
    __syncthreads();

    const float4* h4 = (const float4*)&h_lds[p][0];
    float a0 = 0.f, a1 = 0.f, a2 = 0.f, a3 = 0.f;
    #pragma unroll
    for (int c4 = 0; c4 < 16; ++c4) {
      float4 hv = h4[c4];
      a0 = fmaf(w[4 * c4 + 0], hv.x, a0);
      a1 = fmaf(w[4 * c4 + 1], hv.y, a1);
      a2 = fmaf(w[4 * c4 + 2], hv.z, a2);
      a3 = fmaf(w[4 * c4 + 3], hv.w, a3);
    }
    float acc = (a0 + a1) + (a2 + a3);
    acc += __shfl_xor(acc, 1, 64);
    acc += __shfl_xor(acc, 2, 64);
    acc += __shfl_xor(acc, 4, 64);
    if (p == 0) gates[r] = acc + xgv;
    __syncthreads();

    if (tid < 16) {
      float si = fsigmoid(gates[tid]);
      float sf = fsigmoid(gates[16 + tid]);
      float tg = ftanh(gates[32 + tid]);
      float so = fsigmoid(gates[48 + tid]);
      cstate = fmaf(sf, cstate, si * tg);
      float h = so * ftanh(cstate);
      __hip_atomic_store(hb32 + (size_t)t * 512 + wg * 16 + tid,
                         __float_as_uint(h),
                         __ATOMIC_RELAXED, __HIP_MEMORY_SCOPE_AGENT);
    }
    // h_lds next written only after the top-of-loop barrier; gates rewritten
    // only after next barrier-1 -> 2 barriers/step suffice.
  }
}

// ---------------------------------------------------- pos LSTM (single WG) ----
// H=128: one 512-thr WG per direction. Thread owns 1 gate row (w[128]).
// h lives in LDS; no cross-WG sync, plain global stores of the h history.
__device__ __forceinline__ void pos_body(
    const float* __restrict__ xg, const float* __restrict__ whh,
    float* __restrict__ hbuf, int rev)
{
  const int tid = threadIdx.x;       // gate row 0..511

  __shared__ __align__(16) float h_lds[128];
  __shared__ float gates[512];

  float w[128];
  #pragma unroll
  for (int c = 0; c < 128; ++c)
    w[c] = whh[(size_t)tid * 128 + c];

  float cstate = 0.f;                // valid for tid < 128

  for (int s = 0; s < T_LEN; ++s) {
    const int t = rev ? (T_LEN - 1 - s) : s;
    const float xgv = xg[(size_t)t * 512 + tid];

    if (s == 0 && tid < 128) h_lds[tid] = 0.f;
    __syncthreads();                 // prev nonlin h_lds writes -> this matvec

    const float4* h4 = (const float4*)&h_lds[0];
    float a0 = 0.f, a1 = 0.f, a2 = 0.f, a3 = 0.f;
    #pragma unroll
    for (int c4 = 0; c4 < 32; ++c4) {
      float4 hv = h4[c4];            // broadcast: all lanes same address
      a0 = fmaf(w[4 * c4 + 0], hv.x, a0);
      a1 = fmaf(w[4 * c4 + 1], hv.y, a1);
      a2 = fmaf(w[4 * c4 + 2], hv.z, a2);
      a3 = fmaf(w[4 * c4 + 3], hv.w, a3);
    }
    gates[tid] = ((a0 + a1) + (a2 + a3)) + xgv;
    __syncthreads();

    if (tid < 128) {
      float si = fsigmoid(gates[tid]);
      float sf = fsigmoid(gates[128 + tid]);
      float tg = ftanh(gates[256 + tid]);
      float so = fsigmoid(gates[384 + tid]);
      cstate = fmaf(sf, cstate, si * tg);
      float h = so * ftanh(cstate);
      h_lds[tid] = h;
      hbuf[(size_t)t * 128 + tid] = h;
    }
  }
}

__global__ __launch_bounds__(512, 1) void rec_kernel(
    const float* xg_wf, const float* xg_wb, const float* whh_w,
    float* h_wf, float* h_wb,
    const float* xg_pf, const float* xg_pb, const float* whh_p,
    float* h_pf, float* h_pb)
{
  int b = blockIdx.x;
  if (b < 32)        word_body(b,      xg_wf, whh_w,             h_wf, 0);
  else if (b < 64)   word_body(b - 32, xg_wb, whh_w + 2048 * 512, h_wb, 1);
  else if (b == 64)  pos_body(xg_pf, whh_p,             h_pf, 0);
  else               pos_body(xg_pb, whh_p + 512 * 128, h_pb, 1);
}

// ------------------------------------------------------------------ concat ----
__global__ void concat_k(const float* __restrict__ wf, const float* __restrict__ wb,
                         const float* __restrict__ pf, const float* __restrict__ pb,
                         float* __restrict__ wcat, float* __restrict__ pcat)
{
  const int totw = T_LEN * 1024;
  const int totp = T_LEN * 256;
  int idx = blockIdx.x * blockDim.x + threadIdx.x;
  int stride = gridDim.x * blockDim.x;
  for (int e = idx; e < totw + totp; e += stride) {
    if (e < totw) {
      int t = e >> 10, d = e & 1023;
      wcat[e] = d < 512 ? wf[t * 512 + d] : wb[t * 512 + (d - 512)];
    } else {
      int e2 = e - totw;
      int t = e2 >> 8, d = e2 & 255;
      pcat[e2] = d < 128 ? pf[t * 128 + d] : pb[t * 128 + (d - 128)];
    }
  }
}

// ------------------------------------------------------------- edge scores ----
__global__ __launch_bounds__(256) void edge_s(
    const float* __restrict__ hwf, const float* __restrict__ hwb,
    const float* __restrict__ hpf, const float* __restrict__ hpb,
    const float* __restrict__ ew, float* s1, float* s2)
{
  const int i = blockIdx.x;
  const int tid = threadIdx.x;
  float a1 = 0.f, a2 = 0.f;
  for (int d = tid; d < 1280; d += 256) {
    float hv;
    if (d < 512)       hv = hwf[i * 512 + d];
    else if (d < 1024) hv = hwb[i * 512 + d - 512];
    else if (d < 1152) hv = hpf[i * 128 + d - 1024];
    else               hv = hpb[i * 128 + d - 1152];
    a1 = fmaf(hv, ew[d], a1);
    a2 = fmaf(hv, ew[1280 + d], a2);
  }
  #pragma unroll
  for (int off = 32; off > 0; off >>= 1) {
    a1 += __shfl_xor(a1, off, 64);
    a2 += __shfl_xor(a2, off, 64);
  }
  __shared__ float r1[4], r2[4];
  const int wid = tid >> 6;
  if ((tid & 63) == 0) { r1[wid] = a1; r2[wid] = a2; }
  __syncthreads();
  if (tid == 0) {
    s1[i] = (r1[0] + r1[1]) + (r1[2] + r1[3]);
    s2[i] = (r2[0] + r2[1]) + (r2[2] + r2[3]);
  }
}

__global__ __launch_bounds__(256) void sfill(
    const float* __restrict__ s1, const float* __restrict__ s2,
    const float* __restrict__ eb, float* __restrict__ out)
{
  int e = blockIdx.x * 256 + threadIdx.x;  // 0 .. 1024*1024-1
  int i = e >> 10, j = e & 1023;
  out[e] = (i == j) ? 0.f : s1[i] + s2[j] + eb[0];
}

// ------------------------------------------------------------------ launch ----
extern "C" void kernel_launch(void* const* d_in, const int* in_sizes, int n_in,
                              void* d_out, int out_size, void* d_ws, size_t ws_size,
                              hipStream_t stream)
{
  const float* words   = (const float*)d_in[0];
  const float* pos     = (const float*)d_in[1];
  const float* w_w0_ih = (const float*)d_in[2];
  const float* w_w0_hh = (const float*)d_in[3];
  const float* w_b0_ih = (const float*)d_in[4];
  const float* w_b0_hh = (const float*)d_in[5];
  const float* w_w1_ih = (const float*)d_in[6];
  const float* w_w1_hh = (const float*)d_in[7];
  const float* w_b1_ih = (const float*)d_in[8];
  const float* w_b1_hh = (const float*)d_in[9];
  const float* p_w0_ih = (const float*)d_in[10];
  const float* p_w0_hh = (const float*)d_in[11];
  const float* p_b0_ih = (const float*)d_in[12];
  const float* p_b0_hh = (const float*)d_in[13];
  const float* p_w1_ih = (const float*)d_in[14];
  const float* p_w1_hh = (const float*)d_in[15];
  const float* p_b1_ih = (const float*)d_in[16];
  const float* p_b1_hh = (const float*)d_in[17];
  const float* edge_w  = (const float*)d_in[18];
  const float* edge_b  = (const float*)d_in[19];

  float* ws = (float*)d_ws;
  float* xg_w  = ws;                       // [2][1024][2048] = 4,194,304
  float* xg_p  = ws + 4194304;             // [2][1024][512]  = 1,048,576
  float* hw0_f = ws + 5242880;             // [1024][512] each (word: poisoned)
  float* hw0_b = hw0_f + 524288;
  float* hw1_f = hw0_b + 524288;
  float* hw1_b = hw1_f + 524288;
  float* hp0_f = hw1_b + 524288;           // [1024][128] each (pos: plain)
  float* hp0_b = hp0_f + 131072;
  float* hp1_f = hp0_b + 131072;
  float* hp1_b = hp1_f + 131072;
  float* wcat  = hp1_b + 131072;           // [1024][1024]
  float* pcat  = wcat + 1048576;           // [1024][256]
  float* s1    = pcat + 262144;
  float* s2    = s1 + 1024;

  // 1. poison the 4 word h buffers (data-as-flag sync); every call, since the
  //    harness does not re-poison between graph replays.
  poison_kernel<<<1024, 256, 0, stream>>>((unsigned*)hw0_f, 2097152);

  // 2. layer-0 input projections
  gemm_bt<<<dim3(32, 16, 2), 256, 0, stream>>>(words, w_w0_ih, w_b0_ih, w_b0_hh,
                                               xg_w, 1024, 2048, 512);
  gemm_bt<<<dim3(8, 16, 2), 256, 0, stream>>>(pos, p_w0_ih, p_b0_ih, p_b0_hh,
                                              xg_p, 1024, 512, 128);

  // 3. layer-0 recurrence (word f/b: 64 WGs, pos f/b: 2 WGs; one launch)
  rec_kernel<<<66, 512, 0, stream>>>(xg_w, xg_w + 2097152, w_w0_hh, hw0_f, hw0_b,
                                     xg_p, xg_p + 524288, p_w0_hh, hp0_f, hp0_b);

  // 4. concat layer-0 outputs
  concat_k<<<2048, 256, 0, stream>>>(hw0_f, hw0_b, hp0_f, hp0_b, wcat, pcat);

  // 5. layer-1 input projections (xg buffers reused)
  gemm_bt<<<dim3(32, 16, 2), 256, 0, stream>>>(wcat, w_w1_ih, w_b1_ih, w_b1_hh,
                                               xg_w, 1024, 2048, 1024);
  gemm_bt<<<dim3(8, 16, 2), 256, 0, stream>>>(pcat, p_w1_ih, p_b1_ih, p_b1_hh,
                                              xg_p, 1024, 512, 256);

  // 6. layer-1 recurrence
  rec_kernel<<<66, 512, 0, stream>>>(xg_w, xg_w + 2097152, w_w1_hh, hw1_f, hw1_b,
                                     xg_p, xg_p + 524288, p_w1_hh, hp1_f, hp1_b);

  // 7. edge scores
  edge_s<<<1024, 256, 0, stream>>>(hw1_f, hw1_b, hp1_f, hp1_b, edge_w, s1, s2);
  sfill<<<4096, 256, 0, stream>>>(s1, s2, edge_b, (float*)d_out);
}